// Round 3
// baseline (83354.950 us; speedup 1.0000x reference)
//
#include <hip/hip_runtime.h>

// ---------------------------------------------------------------------------
// Dual-GRU + per-step dot-attention "counterfactual" model, fp32 baseline.
//
//   preA_k : x_emb[t][b][e]  = x[b,t,:] @ w_x2emb + b_x2emb        (400 WGs)
//            x rows staged in LDS (64 rows/tile) - ideal 41 MB x traffic.
//   preB_k : demo, demo@w_ipw precomp, f_tr, inits, maxes-init,
//            zero atomically-updated out regions, zero barrier     (256 WGs)
//   seq_k  : persistent cooperative kernel, 256 WGs x 256 thr, loops t=0..399
//            phase A : gates GEMM (both cells) -> new hidden (ping-pong)
//            phase B1: per-b flash attention over own history + append
//            phase B2: cat GEMM -> f_old/cf_old, running maxes, IPW head
//            3 custom agent-scope barriers per step.
//   post_k : output heads f_h / f_out / cf_out from running maxes.
// ---------------------------------------------------------------------------

#define TT 400
#define BB 256
#define HH 256
#define XEc 32
#define NXc 100
#define SEc 16
#define G3 768
#define KXc 289   // XE + H + 1

// workspace offsets (floats)
constexpr size_t XEMB_O     = 0;
constexpr size_t FBUF_O     = XEMB_O     + (size_t)TT*BB*XEc;   // [b][t][h]
constexpr size_t CFBUF_O    = FBUF_O     + (size_t)BB*TT*HH;
constexpr size_t FHX_O      = CFBUF_O    + (size_t)BB*TT*HH;    // [2][b][h]
constexpr size_t CFHX_O     = FHX_O      + (size_t)2*BB*HH;
constexpr size_t FOLD_O     = CFHX_O     + (size_t)2*BB*HH;
constexpr size_t CFOLD_O    = FOLD_O     + (size_t)2*BB*HH;
constexpr size_t CTXF_O     = CFOLD_O    + (size_t)2*BB*HH;
constexpr size_t CTXCF_O    = CTXF_O     + (size_t)BB*HH;
constexpr size_t DEMO_O     = CTXCF_O    + (size_t)BB*HH;
constexpr size_t DEMOIPW_O  = DEMO_O     + (size_t)BB*SEc;
constexpr size_t TRF_O      = DEMOIPW_O  + (size_t)BB*HH;
constexpr size_t XEMBMAX_O  = TRF_O      + (size_t)BB;
constexpr size_t FOLDMAX_O  = XEMBMAX_O  + (size_t)BB*XEc;
constexpr size_t CFOLDMAX_O = FOLDMAX_O  + (size_t)BB*HH;
constexpr size_t BAR_O      = CFOLDMAX_O + (size_t)BB*HH;

// out offsets (floats)
constexpr size_t IPW_OUT   = 0;          // (T,B,1)
constexpr size_t FOUT_OUT  = 102400;     // (B,1)
constexpr size_t CFOUT_OUT = 102656;     // (B,1)
constexpr size_t FH_OUT    = 102912;     // (B,256)

struct P {
  const float *x, *x_demo, *x_fr, *f_hx0, *cf_hx0;
  const float *w_x2emb, *b_x2emb, *w_static, *b_static;
  const float *wih_f, *whh_f, *bih_f, *bhh_f;
  const float *wih_cf, *whh_cf, *bih_cf, *bhh_cf;
  const float *w_cat_f, *b_cat_f, *w_cat_cf, *b_cat_cf;
  const float *w_ipw, *b_ipw, *w_ipw_out;
  const float *w_of, *b_of, *w_ho_f;
  const float *w_ocf, *b_ocf, *w_ho_cf;
  float *out; float *ws;
};

__device__ __forceinline__ float sigm(float v) { return 1.f / (1.f + expf(-v)); }

// device-wide sense-reversing barrier; requires all 256 WGs co-resident
// (cooperative launch guarantees this). Release-sequence through the RMWs
// gives transitive happens-before; AGENT scope forces cross-XCD cache ops.
__device__ __forceinline__ void gsync(float* ws) {
  __syncthreads();
  if (threadIdx.x == 0) {
    unsigned* bar = reinterpret_cast<unsigned*>(ws + BAR_O);
    unsigned* gen = bar + 1;
    unsigned g = __hip_atomic_load(gen, __ATOMIC_RELAXED, __HIP_MEMORY_SCOPE_AGENT);
    unsigned old = __hip_atomic_fetch_add(bar, 1u, __ATOMIC_ACQ_REL, __HIP_MEMORY_SCOPE_AGENT);
    if (old == 255u) {
      __hip_atomic_store(bar, 0u, __ATOMIC_RELAXED, __HIP_MEMORY_SCOPE_AGENT);
      __hip_atomic_store(gen, g + 1u, __ATOMIC_RELEASE, __HIP_MEMORY_SCOPE_AGENT);
    } else {
      while (__hip_atomic_load(gen, __ATOMIC_ACQUIRE, __HIP_MEMORY_SCOPE_AGENT) == g)
        __builtin_amdgcn_s_sleep(2);
    }
  }
  __syncthreads();
}

// ------------------------- pre kernels -------------------------------------
__global__ __launch_bounds__(256) void preA_k(P p) {
  __shared__ float wle[NXc * XEc];      // 12.8 KB, [f][e]
  __shared__ float xt[64 * NXc];        // 25.6 KB, 64 x rows staged
  float* ws = p.ws;
  const int t = blockIdx.x;
  for (int i = threadIdx.x; i < NXc * XEc; i += 256) wle[i] = p.w_x2emb[i];
  const int e = threadIdx.x & 31, r0 = threadIdx.x >> 5;
  for (int bt = 0; bt < 4; ++bt) {
    __syncthreads();
    for (int i = threadIdx.x; i < 64 * NXc; i += 256) {
      int r = i / NXc, f = i - r * NXc;
      xt[i] = p.x[((size_t)(bt * 64 + r) * TT + t) * NXc + f];
    }
    __syncthreads();
    for (int r = r0; r < 64; r += 8) {
      const float* xr = xt + r * NXc;
      float acc = p.b_x2emb[e];
      for (int f = 0; f < NXc; ++f) acc += xr[f] * wle[f * XEc + e];
      ws[XEMB_O + ((size_t)t * BB + bt * 64 + r) * XEc + e] = acc;
    }
  }
}

__global__ __launch_bounds__(256) void preB_k(P p) {
  float* ws = p.ws;
  const int tid = threadIdx.x;
  const int blk = blockIdx.x;
  if (blk < 32) {                       // xemb running max over t
    int g = blk * 256 + tid;            // g = b*32+e, 0..8191
    int b = g >> 5, e = g & 31;
    float m = -3.4e38f;
    for (int t = 0; t < TT; ++t)
      m = fmaxf(m, ws[XEMB_O + ((size_t)t * BB + b) * XEc + e]);
    ws[XEMBMAX_O + g] = m;
  } else if (blk < 64) {                // zero ipw / f_out / cf_out out region
    int g = (blk - 32) * 256 + tid;
    for (size_t i = g; i < 102912; i += 8192) p.out[i] = 0.f;
  } else if (blk == 64) {               // demo = x_demo @ w_static + b_static
    for (int i = tid; i < BB * SEc; i += 256) {
      int b = i >> 4, se = i & 15;
      float acc = p.b_static[se];
      for (int ns = 0; ns < 5; ++ns) acc += p.x_demo[b * 5 + ns] * p.w_static[ns * SEc + se];
      ws[DEMO_O + i] = acc;
    }
  } else if (blk < 81) {                // demo_ipw[b][j] = demo(b) @ w_ipw[288:304]
    int g = (blk - 65) * 256 + tid;     // 0..4095
    for (int i = g; i < BB * HH; i += 4096) {
      int b = i >> 8, j = i & 255;
      float acc = 0.f;
      for (int se = 0; se < SEc; ++se) {
        float d = p.b_static[se];
        for (int ns = 0; ns < 5; ++ns) d += p.x_demo[b * 5 + ns] * p.w_static[ns * SEc + se];
        acc += d * p.w_ipw[(size_t)(288 + se) * HH + j];
      }
      ws[DEMOIPW_O + i] = acc;
    }
  } else if (blk == 81) {               // f_tr flag per b
    int b = tid;
    float s = 0.f;
    for (int t = 0; t < TT; ++t) s += p.x_fr[(size_t)b * TT + t];
    ws[TRF_O + b] = (s > 0.f) ? 1.f : 0.f;
  } else if (blk < 98) {                // state inits + running-max inits
    int g = (blk - 82) * 256 + tid;     // 0..4095
    for (int i = g; i < 6 * BB * HH; i += 4096) {
      int a = i >> 16, r = i & 65535;
      float vf = p.f_hx0[r], vc = p.cf_hx0[r];
      size_t off; float v;
      switch (a) {
        case 0: off = FHX_O;      v = vf; break;
        case 1: off = CFHX_O;     v = vc; break;
        case 2: off = FOLD_O;     v = vf; break;
        case 3: off = CFOLD_O;    v = vc; break;
        case 4: off = FOLDMAX_O;  v = vf; break;
        default: off = CFOLDMAX_O; v = vc; break;
      }
      ws[off + r] = v;
    }
  } else if (blk == 98) {               // barrier words
    if (tid < 16) ws[BAR_O + tid] = 0.f;
  }
}

// ------------------------- persistent sequential kernel --------------------
__global__ __launch_bounds__(256) void seq_k(P p) {
  __shared__ float lds[12832];          // 51.3 KB, unioned across phases
  float* ws = p.ws;
  const int tid = threadIdx.x;
  const int wg = blockIdx.x;
  const int btile = wg >> 4, slice = wg & 15;
  const int cell = slice >> 3, sl = slice & 7;
  const int b0 = btile * 16;
  const int tb = tid >> 4, tj = tid & 15;

  for (int t = 0; t < TT; ++t) {
    const int rd = t & 1, wr = 1 - rd;

    // ---------------- phase A: GRU gates GEMM + elementwise update ---------
    {
      float* ax = lds;                  // [16][290]
      float* ah = lds + 16 * 290;       // [16][257]
      const float* wih = cell ? p.wih_cf : p.wih_f;
      const float* whh = cell ? p.whh_cf : p.whh_f;
      const float* bih = cell ? p.bih_cf : p.bih_f;
      const float* bhh = cell ? p.bhh_cf : p.bhh_f;
      const float* oldv = ws + (cell ? CFOLD_O : FOLD_O) + (size_t)rd * BB * HH;
      const float* hxv  = ws + (cell ? CFHX_O  : FHX_O ) + (size_t)rd * BB * HH;
      float*       hxn  = ws + (cell ? CFHX_O  : FHX_O ) + (size_t)wr * BB * HH;

      for (int i = tid; i < 16 * KXc; i += 256) {
        int r = i / KXc, k = i - r * KXc; int b = b0 + r; float v;
        if (k < XEc)            v = ws[XEMB_O + ((size_t)t * BB + b) * XEc + k];
        else if (k < XEc + HH)  v = oldv[(size_t)b * HH + (k - XEc)];
        else                    v = cell ? (1.0f - ws[TRF_O + b]) : p.x_fr[(size_t)b * TT + t];
        ax[r * 290 + k] = v;
      }
      for (int i = tid; i < 16 * HH; i += 256) {
        int r = i >> 8, k = i & 255;
        ah[r * 257 + k] = hxv[(size_t)(b0 + r) * HH + k];
      }
      __syncthreads();

      const int jo = sl * 32 + tj * 2;
      float xr0=0,xr1=0,xz0=0,xz1=0,xn0=0,xn1=0;
      const float* axr = ax + tb * 290;
      const float* wp = wih + jo;
      for (int k = 0; k < KXc; ++k) {
        float a = axr[k];
        const float* wk = wp + (size_t)k * G3;
        float2 w0 = *(const float2*)(wk);
        float2 w1 = *(const float2*)(wk + 256);
        float2 w2 = *(const float2*)(wk + 512);
        xr0 += a*w0.x; xr1 += a*w0.y;
        xz0 += a*w1.x; xz1 += a*w1.y;
        xn0 += a*w2.x; xn1 += a*w2.y;
      }
      float hr0=0,hr1=0,hz0=0,hz1=0,hn0=0,hn1=0;
      const float* ahr = ah + tb * 257;
      const float* hp = whh + jo;
      for (int k = 0; k < HH; ++k) {
        float a = ahr[k];
        const float* wk = hp + (size_t)k * G3;
        float2 w0 = *(const float2*)(wk);
        float2 w1 = *(const float2*)(wk + 256);
        float2 w2 = *(const float2*)(wk + 512);
        hr0 += a*w0.x; hr1 += a*w0.y;
        hz0 += a*w1.x; hz1 += a*w1.y;
        hn0 += a*w2.x; hn1 += a*w2.y;
      }
      int b = b0 + tb;
      float hprev0 = ahr[jo], hprev1 = ahr[jo + 1];
      float r0 = sigm(xr0 + bih[jo]       + hr0 + bhh[jo]);
      float r1 = sigm(xr1 + bih[jo + 1]   + hr1 + bhh[jo + 1]);
      float z0 = sigm(xz0 + bih[jo + 256] + hz0 + bhh[jo + 256]);
      float z1 = sigm(xz1 + bih[jo + 257] + hz1 + bhh[jo + 257]);
      float n0 = tanhf(xn0 + bih[jo + 512] + r0 * (hn0 + bhh[jo + 512]));
      float n1 = tanhf(xn1 + bih[jo + 513] + r1 * (hn1 + bhh[jo + 513]));
      hxn[(size_t)b * HH + jo]     = (1.f - z0) * n0 + z0 * hprev0;
      hxn[(size_t)b * HH + jo + 1] = (1.f - z1) * n1 + z1 * hprev1;
    }
    gsync(ws);

    // ---------------- phase B1: per-b flash attention + history append ----
    {
      const int b = wg;
      for (int c = 0; c < 2; ++c) {
        const float* hnew = ws + (c ? CFHX_O : FHX_O) + (size_t)wr * BB * HH + (size_t)b * HH;
        float* buf = ws + (c ? CFBUF_O : FBUF_O) + (size_t)b * TT * HH;
        float* ctx = ws + (c ? CTXCF_O : CTXF_O) + (size_t)b * HH;
        float* q = lds;                 // [256]
        { float v = hnew[tid]; q[tid] = v; buf[(size_t)t * HH + tid] = v; }
        __syncthreads();
        if (t == 0) {
          ctx[tid] = q[tid];            // reference: ctx = h itself at i==0
        } else {
          const int wv = tid >> 6, ln = tid & 63;
          float q0 = q[ln], q1 = q[ln + 64], q2 = q[ln + 128], q3 = q[ln + 192];
          float m = -1e30f, ssum = 0.f, c0 = 0.f, c1 = 0.f, c2 = 0.f, c3 = 0.f;
          for (int tp = wv; tp < t; tp += 4) {
            const float* kr = buf + (size_t)tp * HH;
            float k0 = kr[ln], k1 = kr[ln + 64], k2 = kr[ln + 128], k3 = kr[ln + 192];
            float d = k0 * q0 + k1 * q1 + k2 * q2 + k3 * q3;
            #pragma unroll
            for (int off = 32; off; off >>= 1) d += __shfl_xor(d, off, 64);
            float nm = fmaxf(m, d);
            float al = expf(m - nm);
            float pv = expf(d - nm);
            ssum = ssum * al + pv;
            c0 = c0 * al + pv * k0; c1 = c1 * al + pv * k1;
            c2 = c2 * al + pv * k2; c3 = c3 * al + pv * k3;
            m = nm;
          }
          float* cm = lds + 256; float* cs = lds + 260; float* cc = lds + 264; // [4][256]
          if (ln == 0) { cm[wv] = m; cs[wv] = ssum; }
          cc[wv * 256 + ln]       = c0;
          cc[wv * 256 + ln + 64]  = c1;
          cc[wv * 256 + ln + 128] = c2;
          cc[wv * 256 + ln + 192] = c3;
          __syncthreads();
          float M = fmaxf(fmaxf(cm[0], cm[1]), fmaxf(cm[2], cm[3]));
          float e0 = expf(cm[0] - M), e1 = expf(cm[1] - M);
          float e2 = expf(cm[2] - M), e3 = expf(cm[3] - M);
          float S = cs[0] * e0 + cs[1] * e1 + cs[2] * e2 + cs[3] * e3;
          float num = cc[tid] * e0 + cc[256 + tid] * e1 + cc[512 + tid] * e2 + cc[768 + tid] * e3;
          ctx[tid] = num / S;
        }
        __syncthreads();
      }
    }
    gsync(ws);

    // ---------------- phase B2: cat GEMM + maxes + IPW head ----------------
    {
      float* ct = lds;                  // [16][513]
      float* it = lds + 16 * 513;       // [16][289]
      const float* hnew = ws + (cell ? CFHX_O : FHX_O) + (size_t)wr * BB * HH;
      const float* ctxv = ws + (cell ? CTXCF_O : CTXF_O);
      for (int i = tid; i < 16 * 512; i += 256) {
        int r = i >> 9, k = i & 511; int b = b0 + r;
        ct[r * 513 + k] = (k < 256) ? hnew[(size_t)b * HH + k]
                                    : ctxv[(size_t)b * HH + (k - 256)];
      }
      for (int i = tid; i < 16 * 288; i += 256) {
        int r = i / 288, k = i - r * 288; int b = b0 + r;
        it[r * 289 + k] = (k < 32) ? ws[XEMB_O + ((size_t)t * BB + b) * XEc + k]
                                   : ws[FOLD_O + (size_t)rd * BB * HH + (size_t)b * HH + (k - 32)];
      }
      __syncthreads();

      const int jo = sl * 32 + tj * 2;
      const float* wc = cell ? p.w_cat_cf : p.w_cat_f;
      const float* bc = cell ? p.b_cat_cf : p.b_cat_f;
      float a0 = 0.f, a1 = 0.f;
      const float* ctr = ct + tb * 513;
      const float* wcp = wc + jo;
      for (int k = 0; k < 512; ++k) {
        float a = ctr[k];
        float2 w = *(const float2*)(wcp + (size_t)k * HH);
        a0 += a * w.x; a1 += a * w.y;
      }
      int b = b0 + tb;
      float f0 = tanhf(a0 + bc[jo]), f1 = tanhf(a1 + bc[jo + 1]);
      float* on = ws + (cell ? CFOLD_O : FOLD_O) + (size_t)wr * BB * HH;
      on[(size_t)b * HH + jo]     = f0;
      on[(size_t)b * HH + jo + 1] = f1;
      if (t < TT - 1) {                 // f_old(t) enters f_zx only for t<=T-2
        float* fm = ws + (cell ? CFOLDMAX_O : FOLDMAX_O);
        fm[(size_t)b * HH + jo]     = fmaxf(fm[(size_t)b * HH + jo], f0);
        fm[(size_t)b * HH + jo + 1] = fmaxf(fm[(size_t)b * HH + jo + 1], f1);
      }
      // IPW head for step t: relu([x_emb, f_old(t-1), demo] @ w_ipw + b) @ w_ipw_out
      const int c = slice * 16 + tj;    // 0..255
      float acc = p.b_ipw[c] + ws[DEMOIPW_O + (size_t)b * HH + c];
      const float* itr = it + tb * 289;
      const float* wi = p.w_ipw + c;
      for (int k = 0; k < 288; ++k) acc += itr[k] * wi[(size_t)k * HH];
      float pr = (acc > 0.f) ? acc * p.w_ipw_out[c] : 0.f;
      pr += __shfl_xor(pr, 8, 16);
      pr += __shfl_xor(pr, 4, 16);
      pr += __shfl_xor(pr, 2, 16);
      pr += __shfl_xor(pr, 1, 16);
      if (tj == 0) atomicAdd(p.out + IPW_OUT + (size_t)t * BB + b, pr);
    }
    gsync(ws);
  }
}

// ------------------------- post kernel: output heads -----------------------
__global__ __launch_bounds__(256) void post_k(P p) {
  __shared__ float at[16 * 306];
  float* ws = p.ws;
  const int tid = threadIdx.x;
  const int wg = blockIdx.x;
  const int btile = wg >> 4, slice = wg & 15;
  const int cell = slice >> 3, sl = slice & 7;
  const int b0 = btile * 16;
  const int tb = tid >> 4, tj = tid & 15;

  for (int i = tid; i < 16 * 305; i += 256) {
    int r = i / 305, k = i - r * 305; int b = b0 + r; float v;
    if (k < 32)        v = ws[XEMBMAX_O + (size_t)b * XEc + k];
    else if (k < 288)  v = ws[(cell ? CFOLDMAX_O : FOLDMAX_O) + (size_t)b * HH + (k - 32)];
    else if (k < 304)  v = ws[DEMO_O + (size_t)b * SEc + (k - 288)];
    else { float tr = ws[TRF_O + b]; v = cell ? (1.f - tr) : tr; }
    at[r * 306 + k] = v;
  }
  __syncthreads();

  const int jo = sl * 32 + tj * 2;
  const float* wo  = cell ? p.w_ocf   : p.w_of;
  const float* bo  = cell ? p.b_ocf   : p.b_of;
  const float* who = cell ? p.w_ho_cf : p.w_ho_f;
  float a0 = 0.f, a1 = 0.f;
  const float* ar = at + tb * 306;
  const float* wop = wo + jo;
  for (int k = 0; k < 305; ++k) {
    float a = ar[k];
    float2 w = *(const float2*)(wop + (size_t)k * HH);
    a0 += a * w.x; a1 += a * w.y;
  }
  int b = b0 + tb;
  float h0 = fmaxf(a0 + bo[jo], 0.f), h1 = fmaxf(a1 + bo[jo + 1], 0.f);
  if (!cell) {
    p.out[FH_OUT + (size_t)b * HH + jo]     = h0;
    p.out[FH_OUT + (size_t)b * HH + jo + 1] = h1;
  }
  float pr = h0 * who[jo] + h1 * who[jo + 1];
  pr += __shfl_xor(pr, 8, 16);
  pr += __shfl_xor(pr, 4, 16);
  pr += __shfl_xor(pr, 2, 16);
  pr += __shfl_xor(pr, 1, 16);
  if (tj == 0) atomicAdd(p.out + (cell ? CFOUT_OUT : FOUT_OUT) + b, pr);
}

// ---------------------------------------------------------------------------
extern "C" void kernel_launch(void* const* d_in, const int* in_sizes, int n_in,
                              void* d_out, int out_size, void* d_ws, size_t ws_size,
                              hipStream_t stream) {
  (void)in_sizes; (void)n_in; (void)out_size; (void)ws_size;
  P p;
  p.x        = (const float*)d_in[0];
  p.x_demo   = (const float*)d_in[1];
  p.x_fr     = (const float*)d_in[2];
  p.f_hx0    = (const float*)d_in[3];
  p.cf_hx0   = (const float*)d_in[4];
  p.w_x2emb  = (const float*)d_in[5];
  p.b_x2emb  = (const float*)d_in[6];
  p.w_static = (const float*)d_in[7];
  p.b_static = (const float*)d_in[8];
  p.wih_f    = (const float*)d_in[9];
  p.whh_f    = (const float*)d_in[10];
  p.bih_f    = (const float*)d_in[11];
  p.bhh_f    = (const float*)d_in[12];
  p.wih_cf   = (const float*)d_in[13];
  p.whh_cf   = (const float*)d_in[14];
  p.bih_cf   = (const float*)d_in[15];
  p.bhh_cf   = (const float*)d_in[16];
  p.w_cat_f  = (const float*)d_in[17];
  p.b_cat_f  = (const float*)d_in[18];
  p.w_cat_cf = (const float*)d_in[19];
  p.b_cat_cf = (const float*)d_in[20];
  p.w_ipw    = (const float*)d_in[21];
  p.b_ipw    = (const float*)d_in[22];
  p.w_ipw_out= (const float*)d_in[23];
  p.w_of     = (const float*)d_in[24];
  p.b_of     = (const float*)d_in[25];
  p.w_ho_f   = (const float*)d_in[26];
  p.w_ocf    = (const float*)d_in[27];
  p.b_ocf    = (const float*)d_in[28];
  p.w_ho_cf  = (const float*)d_in[29];
  p.out = (float*)d_out;
  p.ws  = (float*)d_ws;

  preA_k<<<dim3(TT), dim3(256), 0, stream>>>(p);
  preB_k<<<dim3(256), dim3(256), 0, stream>>>(p);

  void* kp[] = { &p };
  hipLaunchCooperativeKernel((const void*)seq_k, dim3(256), dim3(256), kp, 0, stream);

  post_k<<<dim3(256), dim3(256), 0, stream>>>(p);
}

// Round 5
// 67763.916 us; speedup vs baseline: 1.2301x; 1.2301x over previous
//
#include <hip/hip_runtime.h>

// ---------------------------------------------------------------------------
// Dual-GRU + per-step dot-attention "counterfactual" model, fp32.
// R4: seq_k widened 256 -> 1024 threads/WG (16 waves/CU, was 4) to hide
// weight-load latency (R3 counters: VALUBusy 9%, Occupancy 12.4%, 322 GB/s).
// Phase A/B2 GEMMs split-K across thread halves; B1 uses 16 waves + 2-row
// unrolled online softmax.
// ---------------------------------------------------------------------------

#define TT 400
#define BB 256
#define HH 256
#define XEc 32
#define NXc 100
#define SEc 16
#define G3 768
#define KXc 289   // XE + H + 1

// workspace offsets (floats)
constexpr size_t XEMB_O     = 0;
constexpr size_t FBUF_O     = XEMB_O     + (size_t)TT*BB*XEc;   // [b][t][h]
constexpr size_t CFBUF_O    = FBUF_O     + (size_t)BB*TT*HH;
constexpr size_t FHX_O      = CFBUF_O    + (size_t)BB*TT*HH;    // [2][b][h]
constexpr size_t CFHX_O     = FHX_O      + (size_t)2*BB*HH;
constexpr size_t FOLD_O     = CFHX_O     + (size_t)2*BB*HH;
constexpr size_t CFOLD_O    = FOLD_O     + (size_t)2*BB*HH;
constexpr size_t CTXF_O     = CFOLD_O    + (size_t)2*BB*HH;
constexpr size_t CTXCF_O    = CTXF_O     + (size_t)BB*HH;
constexpr size_t DEMO_O     = CTXCF_O    + (size_t)BB*HH;
constexpr size_t DEMOIPW_O  = DEMO_O     + (size_t)BB*SEc;
constexpr size_t TRF_O      = DEMOIPW_O  + (size_t)BB*HH;
constexpr size_t XEMBMAX_O  = TRF_O      + (size_t)BB;
constexpr size_t FOLDMAX_O  = XEMBMAX_O  + (size_t)BB*XEc;
constexpr size_t CFOLDMAX_O = FOLDMAX_O  + (size_t)BB*HH;
constexpr size_t BAR_O      = CFOLDMAX_O + (size_t)BB*HH;

// out offsets (floats)
constexpr size_t IPW_OUT   = 0;          // (T,B,1)
constexpr size_t FOUT_OUT  = 102400;     // (B,1)
constexpr size_t CFOUT_OUT = 102656;     // (B,1)
constexpr size_t FH_OUT    = 102912;     // (B,256)

struct P {
  const float *x, *x_demo, *x_fr, *f_hx0, *cf_hx0;
  const float *w_x2emb, *b_x2emb, *w_static, *b_static;
  const float *wih_f, *whh_f, *bih_f, *bhh_f;
  const float *wih_cf, *whh_cf, *bih_cf, *bhh_cf;
  const float *w_cat_f, *b_cat_f, *w_cat_cf, *b_cat_cf;
  const float *w_ipw, *b_ipw, *w_ipw_out;
  const float *w_of, *b_of, *w_ho_f;
  const float *w_ocf, *b_ocf, *w_ho_cf;
  float *out; float *ws;
};

__device__ __forceinline__ float sigm(float v) { return 1.f / (1.f + expf(-v)); }

// device-wide sense-reversing barrier; requires all 256 WGs co-resident
// (cooperative launch guarantees this). Agent-scope acq-rel for cross-XCD.
__device__ __forceinline__ void gsync(float* ws) {
  __syncthreads();
  if (threadIdx.x == 0) {
    unsigned* bar = reinterpret_cast<unsigned*>(ws + BAR_O);
    unsigned* gen = bar + 1;
    unsigned g = __hip_atomic_load(gen, __ATOMIC_RELAXED, __HIP_MEMORY_SCOPE_AGENT);
    unsigned old = __hip_atomic_fetch_add(bar, 1u, __ATOMIC_ACQ_REL, __HIP_MEMORY_SCOPE_AGENT);
    if (old == 255u) {
      __hip_atomic_store(bar, 0u, __ATOMIC_RELAXED, __HIP_MEMORY_SCOPE_AGENT);
      __hip_atomic_store(gen, g + 1u, __ATOMIC_RELEASE, __HIP_MEMORY_SCOPE_AGENT);
    } else {
      while (__hip_atomic_load(gen, __ATOMIC_ACQUIRE, __HIP_MEMORY_SCOPE_AGENT) == g)
        __builtin_amdgcn_s_sleep(2);
    }
  }
  __syncthreads();
}

// ------------------------- pre kernels -------------------------------------
__global__ __launch_bounds__(256) void preA_k(P p) {
  __shared__ float wle[NXc * XEc];      // [f][e]
  __shared__ float xt[64 * NXc];        // 64 x rows staged
  float* ws = p.ws;
  const int t = blockIdx.x;
  for (int i = threadIdx.x; i < NXc * XEc; i += 256) wle[i] = p.w_x2emb[i];
  const int e = threadIdx.x & 31, r0 = threadIdx.x >> 5;
  for (int bt = 0; bt < 4; ++bt) {
    __syncthreads();
    for (int i = threadIdx.x; i < 64 * NXc; i += 256) {
      int r = i / NXc, f = i - r * NXc;
      xt[i] = p.x[((size_t)(bt * 64 + r) * TT + t) * NXc + f];
    }
    __syncthreads();
    for (int r = r0; r < 64; r += 8) {
      const float* xr = xt + r * NXc;
      float acc = p.b_x2emb[e];
      for (int f = 0; f < NXc; ++f) acc += xr[f] * wle[f * XEc + e];
      ws[XEMB_O + ((size_t)t * BB + bt * 64 + r) * XEc + e] = acc;
    }
  }
}

__global__ __launch_bounds__(256) void preB_k(P p) {
  float* ws = p.ws;
  const int tid = threadIdx.x;
  const int blk = blockIdx.x;
  if (blk < 32) {                       // xemb running max over t
    int g = blk * 256 + tid;            // g = b*32+e
    int b = g >> 5, e = g & 31;
    float m = -3.4e38f;
    for (int t = 0; t < TT; ++t)
      m = fmaxf(m, ws[XEMB_O + ((size_t)t * BB + b) * XEc + e]);
    ws[XEMBMAX_O + g] = m;
  } else if (blk < 64) {                // zero atomically-updated out regions
    int g = (blk - 32) * 256 + tid;
    for (size_t i = g; i < 102912; i += 8192) p.out[i] = 0.f;
  } else if (blk == 64) {               // demo = x_demo @ w_static + b_static
    for (int i = tid; i < BB * SEc; i += 256) {
      int b = i >> 4, se = i & 15;
      float acc = p.b_static[se];
      for (int ns = 0; ns < 5; ++ns) acc += p.x_demo[b * 5 + ns] * p.w_static[ns * SEc + se];
      ws[DEMO_O + i] = acc;
    }
  } else if (blk < 81) {                // demo_ipw[b][j] = demo(b) @ w_ipw[288:304]
    int g = (blk - 65) * 256 + tid;
    for (int i = g; i < BB * HH; i += 4096) {
      int b = i >> 8, j = i & 255;
      float acc = 0.f;
      for (int se = 0; se < SEc; ++se) {
        float d = p.b_static[se];
        for (int ns = 0; ns < 5; ++ns) d += p.x_demo[b * 5 + ns] * p.w_static[ns * SEc + se];
        acc += d * p.w_ipw[(size_t)(288 + se) * HH + j];
      }
      ws[DEMOIPW_O + i] = acc;
    }
  } else if (blk == 81) {               // f_tr flag per b
    int b = tid;
    float s = 0.f;
    for (int t = 0; t < TT; ++t) s += p.x_fr[(size_t)b * TT + t];
    ws[TRF_O + b] = (s > 0.f) ? 1.f : 0.f;
  } else if (blk < 98) {                // state inits + running-max inits
    int g = (blk - 82) * 256 + tid;
    for (int i = g; i < 6 * BB * HH; i += 4096) {
      int a = i >> 16, r = i & 65535;
      float vf = p.f_hx0[r], vc = p.cf_hx0[r];
      size_t off; float v;
      switch (a) {
        case 0: off = FHX_O;      v = vf; break;
        case 1: off = CFHX_O;     v = vc; break;
        case 2: off = FOLD_O;     v = vf; break;
        case 3: off = CFOLD_O;    v = vc; break;
        case 4: off = FOLDMAX_O;  v = vf; break;
        default: off = CFOLDMAX_O; v = vc; break;
      }
      ws[off + r] = v;
    }
  } else if (blk == 98) {               // barrier words
    if (tid < 16) ws[BAR_O + tid] = 0.f;
  }
}

// ------------------------- persistent sequential kernel --------------------
// LDS layout (floats), unioned per phase:
//  A : ax[16][290] @0 (4640) | ah[16][257] @4640 (4112) | red[512*3] @8752
//  B1: q[256] @0 | cm[16] @256 | cs[16] @272 | cc[16*256] @288
//  B2: ct[16][513] @0 (8208) | it[16][289] @8208 (4624) | red2[512] @12832
__global__ __launch_bounds__(1024) void seq_k(P p) {
  __shared__ float lds[13344];          // 53.4 KB
  float* ws = p.ws;
  const int tid = threadIdx.x;
  const int wg = blockIdx.x;
  const int btile = wg >> 4, slice = wg & 15;
  const int cell = slice >> 3, sl = slice & 7;
  const int b0 = btile * 16;
  // GEMM split-K mapping (phases A and B2)
  const int khalf = tid >> 9;           // 0 / 1
  const int gr = (tid & 511) >> 5;      // 0..15 row in btile
  const int gc = tid & 31;              // 0..31 col in slice
  const int jo = sl * 32 + gc;          // 0..255 output column

  for (int t = 0; t < TT; ++t) {
    const int rd = t & 1, wr = 1 - rd;

    // ---------------- phase A: GRU gates GEMM + elementwise update ---------
    {
      float* ax  = lds;                 // [16][290], 289 used
      float* ah  = lds + 4640;          // [16][257], 256 used
      float* red = lds + 8752;          // [512][3]
      const float* oldv = ws + (cell ? CFOLD_O : FOLD_O) + (size_t)rd * BB * HH;
      const float* hxv  = ws + (cell ? CFHX_O  : FHX_O ) + (size_t)rd * BB * HH;
      float*       hxn  = ws + (cell ? CFHX_O  : FHX_O ) + (size_t)wr * BB * HH;

      for (int i = tid; i < 16 * KXc; i += 1024) {
        int r = i / KXc, k = i - r * KXc; int b = b0 + r; float v;
        if (k < XEc)            v = ws[XEMB_O + ((size_t)t * BB + b) * XEc + k];
        else if (k < XEc + HH)  v = oldv[(size_t)b * HH + (k - XEc)];
        else                    v = cell ? (1.0f - ws[TRF_O + b]) : p.x_fr[(size_t)b * TT + t];
        ax[r * 290 + k] = v;
      }
      for (int i = tid; i < 16 * 256; i += 1024) {
        int r = i >> 8, k = i & 255;
        ah[r * 257 + k] = hxv[(size_t)(b0 + r) * HH + k];
      }
      __syncthreads();

      float g0 = 0.f, g1 = 0.f, g2 = 0.f;    // r,z,n partials for (gr, jo)
      if (khalf == 0) {                      // x-part, K=289
        const float* a  = ax + gr * 290;
        const float* wk = (cell ? p.wih_cf : p.wih_f) + jo;
        #pragma unroll 4
        for (int k = 0; k < KXc; ++k) {
          float av = a[k];
          g0 += av * wk[0]; g1 += av * wk[256]; g2 += av * wk[512];
          wk += G3;
        }
      } else {                               // h-part, K=256
        const float* a  = ah + gr * 257;
        const float* wk = (cell ? p.whh_cf : p.whh_f) + jo;
        #pragma unroll 4
        for (int k = 0; k < 256; ++k) {
          float av = a[k];
          g0 += av * wk[0]; g1 += av * wk[256]; g2 += av * wk[512];
          wk += G3;
        }
      }
      if (khalf == 1) {
        float* rp = red + (gr * 32 + gc) * 3;
        rp[0] = g0; rp[1] = g1; rp[2] = g2;
      }
      __syncthreads();
      if (khalf == 0) {
        const float* bih = cell ? p.bih_cf : p.bih_f;
        const float* bhh = cell ? p.bhh_cf : p.bhh_f;
        const float* rp = red + (gr * 32 + gc) * 3;
        float hr = rp[0], hz = rp[1], hn = rp[2];
        float hprev = ah[gr * 257 + jo];
        float r0 = sigm(g0 + bih[jo]       + hr + bhh[jo]);
        float z0 = sigm(g1 + bih[jo + 256] + hz + bhh[jo + 256]);
        float n0 = tanhf(g2 + bih[jo + 512] + r0 * (hn + bhh[jo + 512]));
        hxn[(size_t)(b0 + gr) * HH + jo] = (1.f - z0) * n0 + z0 * hprev;
      }
    }
    gsync(ws);

    // ---------------- phase B1: per-b flash attention + history append ----
    {
      const int b = wg;
      for (int c = 0; c < 2; ++c) {
        const float* hnew = ws + (c ? CFHX_O : FHX_O) + (size_t)wr * BB * HH + (size_t)b * HH;
        float* buf = ws + (c ? CFBUF_O : FBUF_O) + (size_t)b * TT * HH;
        float* ctx = ws + (c ? CTXCF_O : CTXF_O) + (size_t)b * HH;
        float* q = lds;                 // [256]
        if (tid < 256) { float v = hnew[tid]; q[tid] = v; buf[(size_t)t * HH + tid] = v; }
        __syncthreads();
        if (t == 0) {
          if (tid < 256) ctx[tid] = q[tid];
          __syncthreads();
        } else {
          const int wv = tid >> 6, ln = tid & 63;
          float q0 = q[ln], q1 = q[ln + 64], q2 = q[ln + 128], q3 = q[ln + 192];
          float m = -1e30f, ssum = 0.f, c0 = 0.f, c1 = 0.f, c2 = 0.f, c3 = 0.f;
          int tp = wv;
          for (; tp + 16 < t; tp += 32) {       // 2-row unroll (rows tp, tp+16)
            const float* ka = buf + (size_t)tp * HH;
            const float* kb = buf + (size_t)(tp + 16) * HH;
            float a0 = ka[ln], a1 = ka[ln + 64], a2 = ka[ln + 128], a3 = ka[ln + 192];
            float e0 = kb[ln], e1 = kb[ln + 64], e2 = kb[ln + 128], e3 = kb[ln + 192];
            float da = a0 * q0 + a1 * q1 + a2 * q2 + a3 * q3;
            float db = e0 * q0 + e1 * q1 + e2 * q2 + e3 * q3;
            #pragma unroll
            for (int off = 32; off; off >>= 1) {
              da += __shfl_xor(da, off, 64);
              db += __shfl_xor(db, off, 64);
            }
            float nm = fmaxf(m, fmaxf(da, db));
            float al = expf(m - nm), pa = expf(da - nm), pb = expf(db - nm);
            ssum = ssum * al + pa + pb;
            c0 = c0 * al + pa * a0 + pb * e0;
            c1 = c1 * al + pa * a1 + pb * e1;
            c2 = c2 * al + pa * a2 + pb * e2;
            c3 = c3 * al + pa * a3 + pb * e3;
            m = nm;
          }
          if (tp < t) {                          // tail row
            const float* kr = buf + (size_t)tp * HH;
            float a0 = kr[ln], a1 = kr[ln + 64], a2 = kr[ln + 128], a3 = kr[ln + 192];
            float d = a0 * q0 + a1 * q1 + a2 * q2 + a3 * q3;
            #pragma unroll
            for (int off = 32; off; off >>= 1) d += __shfl_xor(d, off, 64);
            float nm = fmaxf(m, d);
            float al = expf(m - nm), pv = expf(d - nm);
            ssum = ssum * al + pv;
            c0 = c0 * al + pv * a0; c1 = c1 * al + pv * a1;
            c2 = c2 * al + pv * a2; c3 = c3 * al + pv * a3;
            m = nm;
          }
          float* cm = lds + 256; float* cs = lds + 272; float* cc = lds + 288;
          if (ln == 0) { cm[wv] = m; cs[wv] = ssum; }
          cc[wv * 256 + ln]       = c0;
          cc[wv * 256 + ln + 64]  = c1;
          cc[wv * 256 + ln + 128] = c2;
          cc[wv * 256 + ln + 192] = c3;
          __syncthreads();
          if (tid < 256) {
            float M = cm[0];
            #pragma unroll
            for (int w2 = 1; w2 < 16; ++w2) M = fmaxf(M, cm[w2]);
            float S = 0.f, num = 0.f;
            #pragma unroll
            for (int w2 = 0; w2 < 16; ++w2) {
              float e = expf(cm[w2] - M);
              S   += cs[w2] * e;
              num += cc[w2 * 256 + tid] * e;
            }
            ctx[tid] = num / S;
          }
          __syncthreads();
        }
      }
    }
    gsync(ws);

    // ---------------- phase B2: cat GEMM + maxes + IPW head ----------------
    {
      float* ct   = lds;                // [16][513], 512 used
      float* it   = lds + 8208;         // [16][289], 288 used
      float* red2 = lds + 12832;        // [512]
      const float* hnew = ws + (cell ? CFHX_O : FHX_O) + (size_t)wr * BB * HH;
      const float* ctxv = ws + (cell ? CTXCF_O : CTXF_O);
      for (int i = tid; i < 16 * 512; i += 1024) {
        int r = i >> 9, k = i & 511; int b = b0 + r;
        ct[r * 513 + k] = (k < 256) ? hnew[(size_t)b * HH + k]
                                    : ctxv[(size_t)b * HH + (k - 256)];
      }
      for (int i = tid; i < 16 * 288; i += 1024) {
        int r = i / 288, k = i - r * 288; int b = b0 + r;
        it[r * 289 + k] = (k < 32) ? ws[XEMB_O + ((size_t)t * BB + b) * XEc + k]
                                   : ws[FOLD_O + (size_t)rd * BB * HH + (size_t)b * HH + (k - 32)];
      }
      __syncthreads();

      // cat GEMM, split-K 2-way
      {
        const float* wc = cell ? p.w_cat_cf : p.w_cat_f;
        float a0 = 0.f;
        const float* ar = ct + gr * 513 + khalf * 256;
        const float* wp = wc + (size_t)(khalf * 256) * HH + jo;
        #pragma unroll 4
        for (int k = 0; k < 256; ++k) { a0 += ar[k] * wp[0]; wp += HH; }
        if (khalf == 1) red2[gr * 32 + gc] = a0;
        __syncthreads();
        if (khalf == 0) {
          const float* bc = cell ? p.b_cat_cf : p.b_cat_f;
          float f0 = tanhf(a0 + red2[gr * 32 + gc] + bc[jo]);
          int b = b0 + gr;
          float* on = ws + (cell ? CFOLD_O : FOLD_O) + (size_t)wr * BB * HH;
          on[(size_t)b * HH + jo] = f0;
          if (t < TT - 1) {               // f_old(t) enters f_zx only for t<=T-2
            float* fm = ws + (cell ? CFOLDMAX_O : FOLDMAX_O);
            fm[(size_t)b * HH + jo] = fmaxf(fm[(size_t)b * HH + jo], f0);
          }
        }
      }
      // IPW head: relu([x_emb, f_old(t-1), demo] @ w_ipw + b) @ w_ipw_out
      {
        const int ir = tid >> 6, il = tid & 63;
        const int itj = il >> 2, ikq = il & 3;    // 16 cols x 4 k-quarters
        const int cI = slice * 16 + itj;
        const int b = b0 + ir;
        float acc = 0.f;
        const float* itr = it + ir * 289;
        const float* wi = p.w_ipw + cI;
        #pragma unroll 4
        for (int k = ikq * 72; k < ikq * 72 + 72; ++k) acc += itr[k] * wi[(size_t)k * HH];
        acc += __shfl_xor(acc, 1, 64);
        acc += __shfl_xor(acc, 2, 64);
        float tot = acc + p.b_ipw[cI] + ws[DEMOIPW_O + (size_t)b * HH + cI];
        float pr = (tot > 0.f) ? tot * p.w_ipw_out[cI] : 0.f;
        pr += __shfl_xor(pr, 4, 64);
        pr += __shfl_xor(pr, 8, 64);
        pr += __shfl_xor(pr, 16, 64);
        pr += __shfl_xor(pr, 32, 64);
        if (il == 0) atomicAdd(p.out + IPW_OUT + (size_t)t * BB + b, pr);
      }
    }
    gsync(ws);
  }
}

// ------------------------- post kernel: output heads -----------------------
__global__ __launch_bounds__(256) void post_k(P p) {
  __shared__ float at[16 * 306];
  float* ws = p.ws;
  const int tid = threadIdx.x;
  const int wg = blockIdx.x;
  const int btile = wg >> 4, slice = wg & 15;
  const int cell = slice >> 3, sl = slice & 7;
  const int b0 = btile * 16;
  const int tb = tid >> 4, tj = tid & 15;

  for (int i = tid; i < 16 * 305; i += 256) {
    int r = i / 305, k = i - r * 305; int b = b0 + r; float v;
    if (k < 32)        v = ws[XEMBMAX_O + (size_t)b * XEc + k];
    else if (k < 288)  v = ws[(cell ? CFOLDMAX_O : FOLDMAX_O) + (size_t)b * HH + (k - 32)];
    else if (k < 304)  v = ws[DEMO_O + (size_t)b * SEc + (k - 288)];
    else { float tr = ws[TRF_O + b]; v = cell ? (1.f - tr) : tr; }
    at[r * 306 + k] = v;
  }
  __syncthreads();

  const int jo = sl * 32 + tj * 2;
  const float* wo  = cell ? p.w_ocf   : p.w_of;
  const float* bo  = cell ? p.b_ocf   : p.b_of;
  const float* who = cell ? p.w_ho_cf : p.w_ho_f;
  float a0 = 0.f, a1 = 0.f;
  const float* ar = at + tb * 306;
  const float* wop = wo + jo;
  for (int k = 0; k < 305; ++k) {
    float a = ar[k];
    float2 w = *(const float2*)(wop + (size_t)k * HH);
    a0 += a * w.x; a1 += a * w.y;
  }
  int b = b0 + tb;
  float h0 = fmaxf(a0 + bo[jo], 0.f), h1 = fmaxf(a1 + bo[jo + 1], 0.f);
  if (!cell) {
    p.out[FH_OUT + (size_t)b * HH + jo]     = h0;
    p.out[FH_OUT + (size_t)b * HH + jo + 1] = h1;
  }
  float pr = h0 * who[jo] + h1 * who[jo + 1];
  pr += __shfl_xor(pr, 8, 16);
  pr += __shfl_xor(pr, 4, 16);
  pr += __shfl_xor(pr, 2, 16);
  pr += __shfl_xor(pr, 1, 16);
  if (tj == 0) atomicAdd(p.out + (cell ? CFOUT_OUT : FOUT_OUT) + b, pr);
}

// ---------------------------------------------------------------------------
extern "C" void kernel_launch(void* const* d_in, const int* in_sizes, int n_in,
                              void* d_out, int out_size, void* d_ws, size_t ws_size,
                              hipStream_t stream) {
  (void)in_sizes; (void)n_in; (void)out_size; (void)ws_size;
  P p;
  p.x        = (const float*)d_in[0];
  p.x_demo   = (const float*)d_in[1];
  p.x_fr     = (const float*)d_in[2];
  p.f_hx0    = (const float*)d_in[3];
  p.cf_hx0   = (const float*)d_in[4];
  p.w_x2emb  = (const float*)d_in[5];
  p.b_x2emb  = (const float*)d_in[6];
  p.w_static = (const float*)d_in[7];
  p.b_static = (const float*)d_in[8];
  p.wih_f    = (const float*)d_in[9];
  p.whh_f    = (const float*)d_in[10];
  p.bih_f    = (const float*)d_in[11];
  p.bhh_f    = (const float*)d_in[12];
  p.wih_cf   = (const float*)d_in[13];
  p.whh_cf   = (const float*)d_in[14];
  p.bih_cf   = (const float*)d_in[15];
  p.bhh_cf   = (const float*)d_in[16];
  p.w_cat_f  = (const float*)d_in[17];
  p.b_cat_f  = (const float*)d_in[18];
  p.w_cat_cf = (const float*)d_in[19];
  p.b_cat_cf = (const float*)d_in[20];
  p.w_ipw    = (const float*)d_in[21];
  p.b_ipw    = (const float*)d_in[22];
  p.w_ipw_out= (const float*)d_in[23];
  p.w_of     = (const float*)d_in[24];
  p.b_of     = (const float*)d_in[25];
  p.w_ho_f   = (const float*)d_in[26];
  p.w_ocf    = (const float*)d_in[27];
  p.b_ocf    = (const float*)d_in[28];
  p.w_ho_cf  = (const float*)d_in[29];
  p.out = (float*)d_out;
  p.ws  = (float*)d_ws;

  preA_k<<<dim3(TT), dim3(256), 0, stream>>>(p);
  preB_k<<<dim3(256), dim3(256), 0, stream>>>(p);

  void* kp[] = { &p };
  hipLaunchCooperativeKernel((const void*)seq_k, dim3(256), dim3(1024), kp, 0, stream);

  post_k<<<dim3(256), dim3(256), 0, stream>>>(p);
}

// Round 9
// 45915.399 us; speedup vs baseline: 1.8154x; 1.4758x over previous
//
#include <hip/hip_runtime.h>

// ---------------------------------------------------------------------------
// Dual-GRU + per-step dot-attention "counterfactual" model, fp32.
// R8: dependency analysis shows ALL cross-WG dependencies in seq_k stay
// within each 16-WG btile group (A: rows b0..b0+15 from same group's B2/A;
// B1 row b from group b>>4's A; B2's ctx rows from same group's B1; buf is
// self-written). So the 1200 device-wide barriers (R5: ~50us each, ~90% of
// runtime) are replaced by 16-WG GROUP barriers: 1 padded release-store +
// 16 parallel acquire-polls (~1 L2 round trip), groups free-run w.r.t. each
// other. Compute phases byte-identical to the R5 PASS kernel.
// ---------------------------------------------------------------------------

#define TT 400
#define BB 256
#define HH 256
#define XEc 32
#define NXc 100
#define SEc 16
#define G3 768
#define KXc 289   // XE + H + 1

// workspace offsets (floats)
constexpr size_t XEMB_O     = 0;
constexpr size_t FBUF_O     = XEMB_O     + (size_t)TT*BB*XEc;   // [b][t][h]
constexpr size_t CFBUF_O    = FBUF_O     + (size_t)BB*TT*HH;
constexpr size_t FHX_O      = CFBUF_O    + (size_t)BB*TT*HH;    // [2][b][h]
constexpr size_t CFHX_O     = FHX_O      + (size_t)2*BB*HH;
constexpr size_t FOLD_O     = CFHX_O     + (size_t)2*BB*HH;
constexpr size_t CFOLD_O    = FOLD_O     + (size_t)2*BB*HH;
constexpr size_t CTXF_O     = CFOLD_O    + (size_t)2*BB*HH;
constexpr size_t CTXCF_O    = CTXF_O     + (size_t)BB*HH;
constexpr size_t DEMO_O     = CTXCF_O    + (size_t)BB*HH;
constexpr size_t DEMOIPW_O  = DEMO_O     + (size_t)BB*SEc;
constexpr size_t TRF_O      = DEMOIPW_O  + (size_t)BB*HH;
constexpr size_t XEMBMAX_O  = TRF_O      + (size_t)BB;
constexpr size_t FOLDMAX_O  = XEMBMAX_O  + (size_t)BB*XEc;
constexpr size_t CFOLDMAX_O = FOLDMAX_O  + (size_t)BB*HH;
constexpr size_t BAR_O      = CFOLDMAX_O + (size_t)BB*HH;
// barrier region: flags[256] @ 16-word (64B) stride = 4096 words
constexpr int    BAR_WORDS  = 4096;

// out offsets (floats)
constexpr size_t IPW_OUT   = 0;          // (T,B,1)
constexpr size_t FOUT_OUT  = 102400;     // (B,1)
constexpr size_t CFOUT_OUT = 102656;     // (B,1)
constexpr size_t FH_OUT    = 102912;     // (B,256)

struct P {
  const float *x, *x_demo, *x_fr, *f_hx0, *cf_hx0;
  const float *w_x2emb, *b_x2emb, *w_static, *b_static;
  const float *wih_f, *whh_f, *bih_f, *bhh_f;
  const float *wih_cf, *whh_cf, *bih_cf, *bhh_cf;
  const float *w_cat_f, *b_cat_f, *w_cat_cf, *b_cat_cf;
  const float *w_ipw, *b_ipw, *w_ipw_out;
  const float *w_of, *b_of, *w_ho_f;
  const float *w_ocf, *b_ocf, *w_ho_cf;
  float *out; float *ws;
};

__device__ __forceinline__ float sigm(float v) { return 1.f / (1.f + expf(-v)); }

// ---------------------------------------------------------------------------
// 16-WG group barrier. Members of group g = wg>>4 are WGs g*16..g*16+15 and
// ALL seq_k cross-WG deps are within a group (see header). Each WG
// release-stores the monotonically increasing `target` to its own padded
// flag; 16 lanes acquire-poll the group's 16 flags. AGENT scope: members may
// sit on different XCDs. Monotonic targets => no reset, no ABA. HB chain:
// writer syncthreads -> release-store -> poller acquire-load -> syncthreads.
// ---------------------------------------------------------------------------
__device__ __forceinline__ void gsyncg(float* ws, int wg, unsigned target) {
  __syncthreads();                      // all phase work done before arrival
  unsigned* flags = reinterpret_cast<unsigned*>(ws + BAR_O);
  const int tid = threadIdx.x;
  if (tid == 0)
    __hip_atomic_store(&flags[wg * 16], target, __ATOMIC_RELEASE, __HIP_MEMORY_SCOPE_AGENT);
  const int gbase = (wg & ~15) * 16;    // flag index of group's first member
  if (tid < 16) {
    while (__hip_atomic_load(&flags[gbase + tid * 16], __ATOMIC_ACQUIRE,
                             __HIP_MEMORY_SCOPE_AGENT) < target)
      __builtin_amdgcn_s_sleep(1);
  }
  __syncthreads();
}

// ------------------------- pre kernels -------------------------------------
__global__ __launch_bounds__(256) void preA_k(P p) {
  __shared__ float wle[NXc * XEc];      // [f][e]
  __shared__ float xt[64 * NXc];        // 64 x rows staged
  float* ws = p.ws;
  const int t = blockIdx.x;
  for (int i = threadIdx.x; i < NXc * XEc; i += 256) wle[i] = p.w_x2emb[i];
  const int e = threadIdx.x & 31, r0 = threadIdx.x >> 5;
  for (int bt = 0; bt < 4; ++bt) {
    __syncthreads();
    for (int i = threadIdx.x; i < 64 * NXc; i += 256) {
      int r = i / NXc, f = i - r * NXc;
      xt[i] = p.x[((size_t)(bt * 64 + r) * TT + t) * NXc + f];
    }
    __syncthreads();
    for (int r = r0; r < 64; r += 8) {
      const float* xr = xt + r * NXc;
      float acc = p.b_x2emb[e];
      for (int f = 0; f < NXc; ++f) acc += xr[f] * wle[f * XEc + e];
      ws[XEMB_O + ((size_t)t * BB + bt * 64 + r) * XEc + e] = acc;
    }
  }
}

__global__ __launch_bounds__(256) void preB_k(P p) {
  float* ws = p.ws;
  const int tid = threadIdx.x;
  const int blk = blockIdx.x;
  if (blk < 32) {                       // xemb running max over t
    int g = blk * 256 + tid;            // g = b*32+e
    int b = g >> 5, e = g & 31;
    float m = -3.4e38f;
    for (int t = 0; t < TT; ++t)
      m = fmaxf(m, ws[XEMB_O + ((size_t)t * BB + b) * XEc + e]);
    ws[XEMBMAX_O + g] = m;
  } else if (blk < 64) {                // zero atomically-updated out regions
    int g = (blk - 32) * 256 + tid;
    for (size_t i = g; i < 102912; i += 8192) p.out[i] = 0.f;
  } else if (blk == 64) {               // demo = x_demo @ w_static + b_static
    for (int i = tid; i < BB * SEc; i += 256) {
      int b = i >> 4, se = i & 15;
      float acc = p.b_static[se];
      for (int ns = 0; ns < 5; ++ns) acc += p.x_demo[b * 5 + ns] * p.w_static[ns * SEc + se];
      ws[DEMO_O + i] = acc;
    }
  } else if (blk < 81) {                // demo_ipw[b][j] = demo(b) @ w_ipw[288:304]
    int g = (blk - 65) * 256 + tid;
    for (int i = g; i < BB * HH; i += 4096) {
      int b = i >> 8, j = i & 255;
      float acc = 0.f;
      for (int se = 0; se < SEc; ++se) {
        float d = p.b_static[se];
        for (int ns = 0; ns < 5; ++ns) d += p.x_demo[b * 5 + ns] * p.w_static[ns * SEc + se];
        acc += d * p.w_ipw[(size_t)(288 + se) * HH + j];
      }
      ws[DEMOIPW_O + i] = acc;
    }
  } else if (blk == 81) {               // f_tr flag per b
    int b = tid;
    float s = 0.f;
    for (int t = 0; t < TT; ++t) s += p.x_fr[(size_t)b * TT + t];
    ws[TRF_O + b] = (s > 0.f) ? 1.f : 0.f;
  } else if (blk < 98) {                // state inits + running-max inits
    int g = (blk - 82) * 256 + tid;
    for (int i = g; i < 6 * BB * HH; i += 4096) {
      int a = i >> 16, r = i & 65535;
      float vf = p.f_hx0[r], vc = p.cf_hx0[r];
      size_t off; float v;
      switch (a) {
        case 0: off = FHX_O;      v = vf; break;
        case 1: off = CFHX_O;     v = vc; break;
        case 2: off = FOLD_O;     v = vf; break;
        case 3: off = CFOLD_O;    v = vc; break;
        case 4: off = FOLDMAX_O;  v = vf; break;
        default: off = CFOLDMAX_O; v = vc; break;
      }
      ws[off + r] = v;
    }
  } else if (blk == 98) {               // zero barrier flag region
    unsigned* bw = reinterpret_cast<unsigned*>(ws + BAR_O);
    for (int i = tid; i < BAR_WORDS; i += 256) bw[i] = 0u;
  }
}

// ------------------------- persistent sequential kernel --------------------
// LDS layout (floats), unioned per phase:
//  A : ax[16][290] @0 (4640) | ah[16][257] @4640 (4112) | red[512*3] @8752
//  B1: q[256] @0 | cm[16] @256 | cs[16] @272 | cc[16*256] @288
//  B2: ct[16][513] @0 (8208) | it[16][289] @8208 (4624) | red2[512] @12832
__global__ __launch_bounds__(1024) void seq_k(P p) {
  __shared__ float lds[13344];          // 53.4 KB
  float* ws = p.ws;
  const int tid = threadIdx.x;
  const int wg = blockIdx.x;
  const int btile = wg >> 4, slice = wg & 15;
  const int cell = slice >> 3, sl = slice & 7;
  const int b0 = btile * 16;
  // GEMM split-K mapping (phases A and B2)
  const int khalf = tid >> 9;           // 0 / 1
  const int gr = (tid & 511) >> 5;      // 0..15 row in btile
  const int gc = tid & 31;              // 0..31 col in slice
  const int jo = sl * 32 + gc;          // 0..255 output column

  unsigned tgt = 1;                     // monotonic barrier target

  for (int t = 0; t < TT; ++t) {
    const int rd = t & 1, wr = 1 - rd;

    // ---------------- phase A: GRU gates GEMM + elementwise update ---------
    {
      float* ax  = lds;                 // [16][290], 289 used
      float* ah  = lds + 4640;          // [16][257], 256 used
      float* red = lds + 8752;          // [512][3]
      const float* oldv = ws + (cell ? CFOLD_O : FOLD_O) + (size_t)rd * BB * HH;
      const float* hxv  = ws + (cell ? CFHX_O  : FHX_O ) + (size_t)rd * BB * HH;
      float*       hxn  = ws + (cell ? CFHX_O  : FHX_O ) + (size_t)wr * BB * HH;

      for (int i = tid; i < 16 * KXc; i += 1024) {
        int r = i / KXc, k = i - r * KXc; int b = b0 + r; float v;
        if (k < XEc)            v = ws[XEMB_O + ((size_t)t * BB + b) * XEc + k];
        else if (k < XEc + HH)  v = oldv[(size_t)b * HH + (k - XEc)];
        else                    v = cell ? (1.0f - ws[TRF_O + b]) : p.x_fr[(size_t)b * TT + t];
        ax[r * 290 + k] = v;
      }
      for (int i = tid; i < 16 * 256; i += 1024) {
        int r = i >> 8, k = i & 255;
        ah[r * 257 + k] = hxv[(size_t)(b0 + r) * HH + k];
      }
      __syncthreads();

      float g0 = 0.f, g1 = 0.f, g2 = 0.f;    // r,z,n partials for (gr, jo)
      if (khalf == 0) {                      // x-part, K=289
        const float* a  = ax + gr * 290;
        const float* wk = (cell ? p.wih_cf : p.wih_f) + jo;
        #pragma unroll 4
        for (int k = 0; k < KXc; ++k) {
          float av = a[k];
          g0 += av * wk[0]; g1 += av * wk[256]; g2 += av * wk[512];
          wk += G3;
        }
      } else {                               // h-part, K=256
        const float* a  = ah + gr * 257;
        const float* wk = (cell ? p.whh_cf : p.whh_f) + jo;
        #pragma unroll 4
        for (int k = 0; k < 256; ++k) {
          float av = a[k];
          g0 += av * wk[0]; g1 += av * wk[256]; g2 += av * wk[512];
          wk += G3;
        }
      }
      if (khalf == 1) {
        float* rp = red + (gr * 32 + gc) * 3;
        rp[0] = g0; rp[1] = g1; rp[2] = g2;
      }
      __syncthreads();
      if (khalf == 0) {
        const float* bih = cell ? p.bih_cf : p.bih_f;
        const float* bhh = cell ? p.bhh_cf : p.bhh_f;
        const float* rp = red + (gr * 32 + gc) * 3;
        float hr = rp[0], hz = rp[1], hn = rp[2];
        float hprev = ah[gr * 257 + jo];
        float r0 = sigm(g0 + bih[jo]       + hr + bhh[jo]);
        float z0 = sigm(g1 + bih[jo + 256] + hz + bhh[jo + 256]);
        float n0 = tanhf(g2 + bih[jo + 512] + r0 * (hn + bhh[jo + 512]));
        hxn[(size_t)(b0 + gr) * HH + jo] = (1.f - z0) * n0 + z0 * hprev;
      }
    }
    gsyncg(ws, wg, tgt++);

    // ---------------- phase B1: per-b flash attention + history append ----
    {
      const int b = wg;
      for (int c = 0; c < 2; ++c) {
        const float* hnew = ws + (c ? CFHX_O : FHX_O) + (size_t)wr * BB * HH + (size_t)b * HH;
        float* buf = ws + (c ? CFBUF_O : FBUF_O) + (size_t)b * TT * HH;
        float* ctx = ws + (c ? CTXCF_O : CTXF_O) + (size_t)b * HH;
        float* q = lds;                 // [256]
        if (tid < 256) { float v = hnew[tid]; q[tid] = v; buf[(size_t)t * HH + tid] = v; }
        __syncthreads();
        if (t == 0) {
          if (tid < 256) ctx[tid] = q[tid];
          __syncthreads();
        } else {
          const int wv = tid >> 6, ln = tid & 63;
          float q0 = q[ln], q1 = q[ln + 64], q2 = q[ln + 128], q3 = q[ln + 192];
          float m = -1e30f, ssum = 0.f, c0 = 0.f, c1 = 0.f, c2 = 0.f, c3 = 0.f;
          int tp = wv;
          for (; tp + 16 < t; tp += 32) {       // 2-row unroll (rows tp, tp+16)
            const float* ka = buf + (size_t)tp * HH;
            const float* kb = buf + (size_t)(tp + 16) * HH;
            float a0 = ka[ln], a1 = ka[ln + 64], a2 = ka[ln + 128], a3 = ka[ln + 192];
            float e0 = kb[ln], e1 = kb[ln + 64], e2 = kb[ln + 128], e3 = kb[ln + 192];
            float da = a0 * q0 + a1 * q1 + a2 * q2 + a3 * q3;
            float db = e0 * q0 + e1 * q1 + e2 * q2 + e3 * q3;
            #pragma unroll
            for (int off = 32; off; off >>= 1) {
              da += __shfl_xor(da, off, 64);
              db += __shfl_xor(db, off, 64);
            }
            float nm = fmaxf(m, fmaxf(da, db));
            float al = expf(m - nm), pa = expf(da - nm), pb = expf(db - nm);
            ssum = ssum * al + pa + pb;
            c0 = c0 * al + pa * a0 + pb * e0;
            c1 = c1 * al + pa * a1 + pb * e1;
            c2 = c2 * al + pa * a2 + pb * e2;
            c3 = c3 * al + pa * a3 + pb * e3;
            m = nm;
          }
          if (tp < t) {                          // tail row
            const float* kr = buf + (size_t)tp * HH;
            float a0 = kr[ln], a1 = kr[ln + 64], a2 = kr[ln + 128], a3 = kr[ln + 192];
            float d = a0 * q0 + a1 * q1 + a2 * q2 + a3 * q3;
            #pragma unroll
            for (int off = 32; off; off >>= 1) d += __shfl_xor(d, off, 64);
            float nm = fmaxf(m, d);
            float al = expf(m - nm), pv = expf(d - nm);
            ssum = ssum * al + pv;
            c0 = c0 * al + pv * a0; c1 = c1 * al + pv * a1;
            c2 = c2 * al + pv * a2; c3 = c3 * al + pv * a3;
            m = nm;
          }
          float* cm = lds + 256; float* cs = lds + 272; float* cc = lds + 288;
          if (ln == 0) { cm[wv] = m; cs[wv] = ssum; }
          cc[wv * 256 + ln]       = c0;
          cc[wv * 256 + ln + 64]  = c1;
          cc[wv * 256 + ln + 128] = c2;
          cc[wv * 256 + ln + 192] = c3;
          __syncthreads();
          if (tid < 256) {
            float M = cm[0];
            #pragma unroll
            for (int w2 = 1; w2 < 16; ++w2) M = fmaxf(M, cm[w2]);
            float S = 0.f, num = 0.f;
            #pragma unroll
            for (int w2 = 0; w2 < 16; ++w2) {
              float e = expf(cm[w2] - M);
              S   += cs[w2] * e;
              num += cc[w2 * 256 + tid] * e;
            }
            ctx[tid] = num / S;
          }
          __syncthreads();
        }
      }
    }
    gsyncg(ws, wg, tgt++);

    // ---------------- phase B2: cat GEMM + maxes + IPW head ----------------
    {
      float* ct   = lds;                // [16][513], 512 used
      float* it   = lds + 8208;         // [16][289], 288 used
      float* red2 = lds + 12832;        // [512]
      const float* hnew = ws + (cell ? CFHX_O : FHX_O) + (size_t)wr * BB * HH;
      const float* ctxv = ws + (cell ? CTXCF_O : CTXF_O);
      for (int i = tid; i < 16 * 512; i += 1024) {
        int r = i >> 9, k = i & 511; int b = b0 + r;
        ct[r * 513 + k] = (k < 256) ? hnew[(size_t)b * HH + k]
                                    : ctxv[(size_t)b * HH + (k - 256)];
      }
      for (int i = tid; i < 16 * 288; i += 1024) {
        int r = i / 288, k = i - r * 288; int b = b0 + r;
        it[r * 289 + k] = (k < 32) ? ws[XEMB_O + ((size_t)t * BB + b) * XEc + k]
                                   : ws[FOLD_O + (size_t)rd * BB * HH + (size_t)b * HH + (k - 32)];
      }
      __syncthreads();

      // cat GEMM, split-K 2-way
      {
        const float* wc = cell ? p.w_cat_cf : p.w_cat_f;
        float a0 = 0.f;
        const float* ar = ct + gr * 513 + khalf * 256;
        const float* wp = wc + (size_t)(khalf * 256) * HH + jo;
        #pragma unroll 4
        for (int k = 0; k < 256; ++k) { a0 += ar[k] * wp[0]; wp += HH; }
        if (khalf == 1) red2[gr * 32 + gc] = a0;
        __syncthreads();
        if (khalf == 0) {
          const float* bc = cell ? p.b_cat_cf : p.b_cat_f;
          float f0 = tanhf(a0 + red2[gr * 32 + gc] + bc[jo]);
          int b = b0 + gr;
          float* on = ws + (cell ? CFOLD_O : FOLD_O) + (size_t)wr * BB * HH;
          on[(size_t)b * HH + jo] = f0;
          if (t < TT - 1) {               // f_old(t) enters f_zx only for t<=T-2
            float* fm = ws + (cell ? CFOLDMAX_O : FOLDMAX_O);
            fm[(size_t)b * HH + jo] = fmaxf(fm[(size_t)b * HH + jo], f0);
          }
        }
      }
      // IPW head: relu([x_emb, f_old(t-1), demo] @ w_ipw + b) @ w_ipw_out
      {
        const int ir = tid >> 6, il = tid & 63;
        const int itj = il >> 2, ikq = il & 3;    // 16 cols x 4 k-quarters
        const int cI = slice * 16 + itj;
        const int b = b0 + ir;
        float acc = 0.f;
        const float* itr = it + ir * 289;
        const float* wi = p.w_ipw + cI;
        #pragma unroll 4
        for (int k = ikq * 72; k < ikq * 72 + 72; ++k) acc += itr[k] * wi[(size_t)k * HH];
        acc += __shfl_xor(acc, 1, 64);
        acc += __shfl_xor(acc, 2, 64);
        float tot = acc + p.b_ipw[cI] + ws[DEMOIPW_O + (size_t)b * HH + cI];
        float pr = (tot > 0.f) ? tot * p.w_ipw_out[cI] : 0.f;
        pr += __shfl_xor(pr, 4, 64);
        pr += __shfl_xor(pr, 8, 64);
        pr += __shfl_xor(pr, 16, 64);
        pr += __shfl_xor(pr, 32, 64);
        if (il == 0) atomicAdd(p.out + IPW_OUT + (size_t)t * BB + b, pr);
      }
    }
    gsyncg(ws, wg, tgt++);
  }
}

// ------------------------- post kernel: output heads -----------------------
__global__ __launch_bounds__(256) void post_k(P p) {
  __shared__ float at[16 * 306];
  float* ws = p.ws;
  const int tid = threadIdx.x;
  const int wg = blockIdx.x;
  const int btile = wg >> 4, slice = wg & 15;
  const int cell = slice >> 3, sl = slice & 7;
  const int b0 = btile * 16;
  const int tb = tid >> 4, tj = tid & 15;

  for (int i = tid; i < 16 * 305; i += 256) {
    int r = i / 305, k = i - r * 305; int b = b0 + r; float v;
    if (k < 32)        v = ws[XEMBMAX_O + (size_t)b * XEc + k];
    else if (k < 288)  v = ws[(cell ? CFOLDMAX_O : FOLDMAX_O) + (size_t)b * HH + (k - 32)];
    else if (k < 304)  v = ws[DEMO_O + (size_t)b * SEc + (k - 288)];
    else { float tr = ws[TRF_O + b]; v = cell ? (1.f - tr) : tr; }
    at[r * 306 + k] = v;
  }
  __syncthreads();

  const int jo = sl * 32 + tj * 2;
  const float* wo  = cell ? p.w_ocf   : p.w_of;
  const float* bo  = cell ? p.b_ocf   : p.b_of;
  const float* who = cell ? p.w_ho_cf : p.w_ho_f;
  float a0 = 0.f, a1 = 0.f;
  const float* ar = at + tb * 306;
  const float* wop = wo + jo;
  for (int k = 0; k < 305; ++k) {
    float a = ar[k];
    float2 w = *(const float2*)(wop + (size_t)k * HH);
    a0 += a * w.x; a1 += a * w.y;
  }
  int b = b0 + tb;
  float h0 = fmaxf(a0 + bo[jo], 0.f), h1 = fmaxf(a1 + bo[jo + 1], 0.f);
  if (!cell) {
    p.out[FH_OUT + (size_t)b * HH + jo]     = h0;
    p.out[FH_OUT + (size_t)b * HH + jo + 1] = h1;
  }
  float pr = h0 * who[jo] + h1 * who[jo + 1];
  pr += __shfl_xor(pr, 8, 16);
  pr += __shfl_xor(pr, 4, 16);
  pr += __shfl_xor(pr, 2, 16);
  pr += __shfl_xor(pr, 1, 16);
  if (tj == 0) atomicAdd(p.out + (cell ? CFOUT_OUT : FOUT_OUT) + b, pr);
}

// ---------------------------------------------------------------------------
extern "C" void kernel_launch(void* const* d_in, const int* in_sizes, int n_in,
                              void* d_out, int out_size, void* d_ws, size_t ws_size,
                              hipStream_t stream) {
  (void)in_sizes; (void)n_in; (void)out_size; (void)ws_size;
  P p;
  p.x        = (const float*)d_in[0];
  p.x_demo   = (const float*)d_in[1];
  p.x_fr     = (const float*)d_in[2];
  p.f_hx0    = (const float*)d_in[3];
  p.cf_hx0   = (const float*)d_in[4];
  p.w_x2emb  = (const float*)d_in[5];
  p.b_x2emb  = (const float*)d_in[6];
  p.w_static = (const float*)d_in[7];
  p.b_static = (const float*)d_in[8];
  p.wih_f    = (const float*)d_in[9];
  p.whh_f    = (const float*)d_in[10];
  p.bih_f    = (const float*)d_in[11];
  p.bhh_f    = (const float*)d_in[12];
  p.wih_cf   = (const float*)d_in[13];
  p.whh_cf   = (const float*)d_in[14];
  p.bih_cf   = (const float*)d_in[15];
  p.bhh_cf   = (const float*)d_in[16];
  p.w_cat_f  = (const float*)d_in[17];
  p.b_cat_f  = (const float*)d_in[18];
  p.w_cat_cf = (const float*)d_in[19];
  p.b_cat_cf = (const float*)d_in[20];
  p.w_ipw    = (const float*)d_in[21];
  p.b_ipw    = (const float*)d_in[22];
  p.w_ipw_out= (const float*)d_in[23];
  p.w_of     = (const float*)d_in[24];
  p.b_of     = (const float*)d_in[25];
  p.w_ho_f   = (const float*)d_in[26];
  p.w_ocf    = (const float*)d_in[27];
  p.b_ocf    = (const float*)d_in[28];
  p.w_ho_cf  = (const float*)d_in[29];
  p.out = (float*)d_out;
  p.ws  = (float*)d_ws;

  preA_k<<<dim3(TT), dim3(256), 0, stream>>>(p);
  preB_k<<<dim3(256), dim3(256), 0, stream>>>(p);

  void* kp[] = { &p };
  hipLaunchCooperativeKernel((const void*)seq_k, dim3(256), dim3(1024), kp, 0, stream);

  post_k<<<dim3(256), dim3(256), 0, stream>>>(p);
}